// Round 3
// baseline (580.652 us; speedup 1.0000x reference)
//
#include <hip/hip_runtime.h>
#include <math.h>

// ---------------------------------------------------------------------------
// EnvelopeDetector via MFMA Toeplitz FIR.
//   conv1(K=100) -> BN(train) -> abs -> conv2(K=50)+bias
//   x:[32,64,20000] f32 -> out:[32,64,19852] f32
// C[i][j] = sum_s A_s[i][k] B_s[k][j];  A_s[i][k]=w(32s+k-i), B_s[k][j]=x(t0+32s+k+16j)
//   => C[i][j] = y(t0 + i + 16j).   C/D layout: col=lane&15, row=(lane>>4)*4+reg.
// ---------------------------------------------------------------------------

constexpr int B_ = 32, C_ = 64, T_ = 20000;
constexpr int K1 = 100, K2 = 50;
constexpr int T1 = T_ - K1 + 1;   // 19901
constexpr int T2 = T1 - K2 + 1;   // 19852
constexpr float EPS = 1e-5f;

constexpr int CHUNK = 4096;       // z/y range per block
constexpr int NCHUNK = 5;         // 5*4096 = 20480 >= T1
constexpr int NUT = 17;           // u-tiles per block (4096+49 halo -> 17*256)
constexpr int UELEMS = NUT * 256; // 4352

typedef __bf16 bf16x8 __attribute__((ext_vector_type(8)));
typedef float f32x4 __attribute__((ext_vector_type(4)));

#define DEVFN __device__ __forceinline__
#define MFMA16(a, b, c) __builtin_amdgcn_mfma_f32_16x16x32_bf16((a), (b), (c), 0, 0, 0)

union FragBits { unsigned short u[8]; bf16x8 v; };

// Toeplitz A fragment: A_s[i][k] = w(32s + k - i), lane i=lane&15, k=8*(lane>>4)+e.
DEVFN bf16x8 toepA_hi(const float* __restrict__ w, int K, int s, int lane) {
  const int i = lane & 15, q = lane >> 4;
  bf16x8 f;
#pragma unroll
  for (int e = 0; e < 8; ++e) {
    const int idx = 32 * s + 8 * q + e - i;
    const float v = (idx >= 0 && idx < K) ? w[idx] : 0.f;
    f[e] = (__bf16)v;
  }
  return f;
}
DEVFN bf16x8 toepA_res(const float* __restrict__ w, int K, int s, int lane) {
  const int i = lane & 15, q = lane >> 4;
  bf16x8 f;
#pragma unroll
  for (int e = 0; e < 8; ++e) {
    const int idx = 32 * s + 8 * q + e - i;
    const float v = (idx >= 0 && idx < K) ? w[idx] : 0.f;
    const float h = (float)(__bf16)v;
    f[e] = (__bf16)(v - h);
  }
  return f;
}

// LDS granule swizzle (8B granules, bijective within 64-granule windows).
DEVFN int swzg(int g) { return (g & ~63) | ((g ^ ((g >> 2) & 15)) & 63); }

__global__ void zero_stats(float* __restrict__ s) { s[threadIdx.x] = 0.f; }

// ---------------- Pass A: conv1 (bf16 single-chain) -> per-channel stats ----
__global__ __launch_bounds__(256) void passA(
    const float* __restrict__ x, const float* __restrict__ wband,
    float* __restrict__ stats) {
  __shared__ float wlds[K1];
  const int tid = threadIdx.x, lane = tid & 63, wid = tid >> 6;
  const int chunk = blockIdx.x, c = blockIdx.y, b = blockIdx.z;
  const float* __restrict__ xrow = x + ((long)(b * C_ + c)) * T_;

  for (int i = tid; i < K1; i += 256) wlds[i] = wband[c * K1 + i];
  __syncthreads();

  bf16x8 A1[4];
#pragma unroll
  for (int s = 0; s < 4; ++s) A1[s] = toepA_hi(wlds, K1, s, lane);

  const int q = lane >> 4, m = lane & 15;
  const int z0 = chunk * CHUNK;
  float s1 = 0.f, s2 = 0.f;

  for (int p = 0; p < 4; ++p) {
    const int t0 = z0 + (wid * 4 + p) * 256;
    if (t0 >= T1) break;
    float xv[4][8];
#pragma unroll
    for (int s = 0; s < 4; ++s) {
      const int base = min(t0 + 32 * s + 8 * q + 16 * m, T_ - 8);
      *(float4*)&xv[s][0] = *(const float4*)&xrow[base];
      *(float4*)&xv[s][4] = *(const float4*)&xrow[base + 4];
    }
    f32x4 acc = {0.f, 0.f, 0.f, 0.f};
#pragma unroll
    for (int s = 0; s < 4; ++s) {
      bf16x8 bh;
#pragma unroll
      for (int e = 0; e < 8; ++e) bh[e] = (__bf16)xv[s][e];
      acc = MFMA16(A1[s], bh, acc);
    }
#pragma unroll
    for (int r = 0; r < 4; ++r) {
      const int t = t0 + 4 * q + r + 16 * m;
      const float y = (t < T1) ? acc[r] : 0.f;
      s1 += y;
      s2 = fmaf(y, y, s2);
    }
  }
#pragma unroll
  for (int off = 32; off > 0; off >>= 1) {
    s1 += __shfl_down(s1, off);
    s2 += __shfl_down(s2, off);
  }
  if (lane == 0) {
    atomicAdd(&stats[c], s1);
    atomicAdd(&stats[C_ + c], s2);
  }
}

// ---------------- stats -> per-channel scale/shift --------------------------
__global__ void finalize_stats(const float* __restrict__ stats,
                               const float* __restrict__ gamma,
                               const float* __restrict__ beta,
                               float* __restrict__ ss) {
  const int c = threadIdx.x;
  if (c < C_) {
    const double N = (double)B_ * (double)T1;
    const double mean = (double)stats[c] / N;
    const double var = (double)stats[C_ + c] / N - mean * mean;
    const float scale = gamma[c] * (float)(1.0 / sqrt(var + (double)EPS));
    const float shift = beta[c] - (float)mean * scale;
    ss[c] = scale;
    ss[C_ + c] = shift;
  }
}

// ---------------- Pass B: conv1(split) -> BN/abs -> u(LDS) -> conv2(split) --
__global__ __launch_bounds__(256) void passB(
    const float* __restrict__ x, const float* __restrict__ wband,
    const float* __restrict__ wlow, const float* __restrict__ blow,
    const float* __restrict__ ss, float* __restrict__ out) {
  __shared__ float wlds[K1];
  __shared__ float wl2[K2];
  __shared__ unsigned short uS[UELEMS];

  const int tid = threadIdx.x, lane = tid & 63, wid = tid >> 6;
  const int chunk = blockIdx.x, c = blockIdx.y, b = blockIdx.z;
  const float* __restrict__ xrow = x + ((long)(b * C_ + c)) * T_;

  for (int i = tid; i < K1; i += 256) wlds[i] = wband[c * K1 + i];
  for (int i = tid; i < K2; i += 256) wl2[i] = wlow[c * K2 + i];
  __syncthreads();

  bf16x8 A1h[4], A1l[4], A2h[3], A2r[3];
#pragma unroll
  for (int s = 0; s < 4; ++s) {
    A1h[s] = toepA_hi(wlds, K1, s, lane);
    A1l[s] = toepA_res(wlds, K1, s, lane);
  }
#pragma unroll
  for (int s = 0; s < 3; ++s) {
    A2h[s] = toepA_hi(wl2, K2, s, lane);
    A2r[s] = toepA_res(wl2, K2, s, lane);
  }

  const float scale = ss[c], shift = ss[C_ + c];
  const int q = lane >> 4, m = lane & 15;
  const int z0 = chunk * CHUNK;

  // ---- u-phase: 17 u-tiles, waves get {5,4,4,4} contiguous tiles ----------
  const int pstart = (wid == 0) ? 0 : (1 + wid * 4);
  const int pcount = (wid == 0) ? 5 : 4;
  for (int pi = 0; pi < pcount; ++pi) {
    const int p = pstart + pi;
    const int t0 = z0 + p * 256;
    float xv[4][8];
#pragma unroll
    for (int s = 0; s < 4; ++s) {
      const int base = min(t0 + 32 * s + 8 * q + 16 * m, T_ - 8);
      *(float4*)&xv[s][0] = *(const float4*)&xrow[base];
      *(float4*)&xv[s][4] = *(const float4*)&xrow[base + 4];
    }
    f32x4 acc = {0.f, 0.f, 0.f, 0.f};
#pragma unroll
    for (int s = 0; s < 4; ++s) {
      bf16x8 bh, bl;
#pragma unroll
      for (int e = 0; e < 8; ++e) {
        const float v = xv[s][e];
        const __bf16 h = (__bf16)v;
        bh[e] = h;
        bl[e] = (__bf16)(v - (float)h);
      }
      acc = MFMA16(A1h[s], bh, acc);
      acc = MFMA16(A1l[s], bh, acc);
      acc = MFMA16(A1h[s], bl, acc);
    }
    // BN + abs -> bf16, one ds_write_b64 of 4 consecutive u.
    FragBits ub;
#pragma unroll
    for (int r = 0; r < 4; ++r) {
      const float u = fabsf(fmaf(acc[r], scale, shift));
      ub.u[r] = __builtin_bit_cast(unsigned short, (__bf16)u);
    }
    const int E = p * 256 + 4 * q + 16 * m;     // granule-aligned (E%4==0)
    *(ushort4*)&uS[swzg(E >> 2) << 2] = *(ushort4*)&ub.u[0];
  }
  __syncthreads();

  // ---- z-phase: 16 z-tiles, 4 per wave ------------------------------------
  float* __restrict__ orow = out + ((long)(b * C_ + c)) * T2;
  const float bl0 = blow[c];
  for (int zi = 0; zi < 4; ++zi) {
    const int t0 = z0 + (wid * 4 + zi) * 256;
    if (t0 >= T2) break;
    f32x4 acc = {0.f, 0.f, 0.f, 0.f};
#pragma unroll
    for (int s = 0; s < 3; ++s) {
      const int E = (t0 - z0) + 32 * s + 8 * q + 16 * m;
      const int g0 = E >> 2;
      FragBits fb;
      *(ushort4*)&fb.u[0] = *(const ushort4*)&uS[swzg(g0) << 2];
      *(ushort4*)&fb.u[4] = *(const ushort4*)&uS[swzg(g0 + 1) << 2];
      acc = MFMA16(A2h[s], fb.v, acc);
      acc = MFMA16(A2r[s], fb.v, acc);
    }
    const int t = t0 + 4 * q + 16 * m;
    if (t0 + 255 < T2) {
      float4 v;
      v.x = acc[0] + bl0; v.y = acc[1] + bl0;
      v.z = acc[2] + bl0; v.w = acc[3] + bl0;
      *(float4*)&orow[t] = v;
    } else {
#pragma unroll
      for (int r = 0; r < 4; ++r)
        if (t + r < T2) orow[t + r] = acc[r] + bl0;
    }
  }
}

extern "C" void kernel_launch(void* const* d_in, const int* in_sizes, int n_in,
                              void* d_out, int out_size, void* d_ws, size_t ws_size,
                              hipStream_t stream) {
  const float* x = (const float*)d_in[0];
  const float* wband = (const float*)d_in[1];
  const float* gamma = (const float*)d_in[2];
  const float* beta = (const float*)d_in[3];
  const float* wlow = (const float*)d_in[4];
  const float* blow = (const float*)d_in[5];
  float* out = (float*)d_out;
  float* ws = (float*)d_ws;

  float* stats = ws;        // 128 floats: sum, sumsq
  float* ss = ws + 128;     // 128 floats: scale, shift

  zero_stats<<<1, 128, 0, stream>>>(stats);

  dim3 grid(NCHUNK, C_, B_);
  passA<<<grid, 256, 0, stream>>>(x, wband, stats);
  finalize_stats<<<1, 64, 0, stream>>>(stats, gamma, beta, ss);
  passB<<<grid, 256, 0, stream>>>(x, wband, wlow, blow, ss, out);
}